// Round 14
// baseline (144.407 us; speedup 1.0000x reference)
//
#include <hip/hip_runtime.h>
#include <math.h>

#define C_CH   256
#define HW     4096              // H*W
#define B_N    32
#define N_PER_CH (B_N * HW)      // 131072
#define N_TOT  ((size_t)B_N * C_CH * HW) // 33554432 per plane
#define EPS_BN 1e-5f

#define NT 512                   // threads per block
#define HALF 16                  // slabs per block (half a channel)
#define RS 9                     // slabs retained in registers (bf16, 72 u32)
#define LS 4                     // slabs retained in LDS (bf16, 64 KiB)
// streamed = 16-9-4 = 3 slabs/block (48 MB chip-wide -> L3-served re-read)

typedef float f32x4 __attribute__((ext_vector_type(4)));

// bf16 round-to-nearest-even pack/unpack (2 values per u32)
__device__ __forceinline__ unsigned pk(float a, float b) {
    unsigned ua = __float_as_uint(a);
    unsigned ub = __float_as_uint(b);
    ua += 0x7fffu + ((ua >> 16) & 1u);
    ub += 0x7fffu + ((ub >> 16) & 1u);
    return (ua >> 16) | (ub & 0xffff0000u);
}
__device__ __forceinline__ float blo(unsigned p) { return __uint_as_float(p << 16); }
__device__ __forceinline__ float bhi(unsigned p) { return __uint_as_float(p & 0xffff0000u); }

// ---------------------------------------------------------------------------
// 16-waves/CU retention via TWO 512-thread blocks per CU.
// Evidence: 1024-thr blocks are hard-capped at 64 VGPRs (R6/R10/R13 all
// spilled); 8 waves/CU only sustains ~5.3 TB/s (R11/R12); 16 waves/CU
// sustains 6.26 TB/s (R9).  __launch_bounds__(512,4) -> V<=128/thread,
// LDS 64 KiB/block -> 2 blocks/CU co-resident = 16 waves/CU.
// Block b = (channel c = b>>1, half h = b&1) owns slabs h*16..h*16+15.
// Thread owns f32x4 t and 512+t of each plane of each slab.
//   regs: 9 slabs  (rp[9][8] = 72 data u32; +~35 ovh ~= 110 <= 128)
//   LDS : 4 slabs  ([4][8][512] u32 = 64 KiB)
//   HBM : 3 slabs  streamed; re-read FIRST in phase 2 (48 MB << L3, hits)
// Cross-half stats combine: R8's flag-spin (device-scope atomics,
// 2-term add = order-independent, empirically deadlock-free).
// Stats from full-precision values; retained copy bf16 (absmax 0.031).
// Output layout [2,B,C,H,W]: real plane, imag plane at +N_TOT.
// ---------------------------------------------------------------------------
__global__ __launch_bounds__(NT, 4) void cbn_dual(
    const float* __restrict__ xr, const float* __restrict__ xi,
    const float* __restrict__ weight,   // [2,2,C]
    const float* __restrict__ bias,     // [2,C]
    float* __restrict__ out,
    float* __restrict__ part,           // [512][5]
    int*   __restrict__ flag)           // [512]
{
    const int b  = blockIdx.x;
    const int c  = b >> 1;
    const int h  = b & 1;
    const int t  = threadIdx.x;
    const int j0 = h * HALF;

    const f32x4* r4 = reinterpret_cast<const f32x4*>(xr);
    const f32x4* i4 = reinterpret_cast<const f32x4*>(xi);

    __shared__ unsigned lpk[LS][8][NT];
    __shared__ float red[5][NT / 64];
    __shared__ float scoef[6];

    float sr = 0.f, si = 0.f, srr = 0.f, sii = 0.f, sri = 0.f;
    unsigned rp[RS][8];

#define ACC(a, bb)                                              \
    sr  += a.x + a.y + a.z + a.w;                               \
    si  += bb.x + bb.y + bb.z + bb.w;                           \
    srr += a.x*a.x + a.y*a.y + a.z*a.z + a.w*a.w;               \
    sii += bb.x*bb.x + bb.y*bb.y + bb.z*bb.z + bb.w*bb.w;       \
    sri += a.x*bb.x + a.y*bb.y + a.z*bb.z + a.w*bb.w;

    // ---- phase 1a: register-retained slabs (bf16-packed, nt loads) ---------
#pragma unroll
    for (int j = 0; j < RS; ++j) {
        const size_t base = ((size_t)((j0 + j) * C_CH + c) << 10);
        const f32x4 a0 = __builtin_nontemporal_load(&r4[base + t]);
        const f32x4 a1 = __builtin_nontemporal_load(&r4[base + NT + t]);
        const f32x4 b0 = __builtin_nontemporal_load(&i4[base + t]);
        const f32x4 b1 = __builtin_nontemporal_load(&i4[base + NT + t]);
        rp[j][0] = pk(a0.x, a0.y); rp[j][1] = pk(a0.z, a0.w);
        rp[j][2] = pk(a1.x, a1.y); rp[j][3] = pk(a1.z, a1.w);
        rp[j][4] = pk(b0.x, b0.y); rp[j][5] = pk(b0.z, b0.w);
        rp[j][6] = pk(b1.x, b1.y); rp[j][7] = pk(b1.z, b1.w);
        ACC(a0, b0) ACC(a1, b1)
    }
    // ---- phase 1b: LDS-retained slabs (bf16-packed, nt loads) --------------
#pragma unroll
    for (int j = 0; j < LS; ++j) {
        const size_t base = ((size_t)((j0 + RS + j) * C_CH + c) << 10);
        const f32x4 a0 = __builtin_nontemporal_load(&r4[base + t]);
        const f32x4 a1 = __builtin_nontemporal_load(&r4[base + NT + t]);
        const f32x4 b0 = __builtin_nontemporal_load(&i4[base + t]);
        const f32x4 b1 = __builtin_nontemporal_load(&i4[base + NT + t]);
        lpk[j][0][t] = pk(a0.x, a0.y); lpk[j][1][t] = pk(a0.z, a0.w);
        lpk[j][2][t] = pk(a1.x, a1.y); lpk[j][3][t] = pk(a1.z, a1.w);
        lpk[j][4][t] = pk(b0.x, b0.y); lpk[j][5][t] = pk(b0.z, b0.w);
        lpk[j][6][t] = pk(b1.x, b1.y); lpk[j][7][t] = pk(b1.z, b1.w);
        ACC(a0, b0) ACC(a1, b1)
    }
    // ---- phase 1c: streamed slabs (temporal -> allocate L3 for re-read) ----
#pragma unroll
    for (int j = RS + LS; j < HALF; ++j) {
        const size_t base = ((size_t)((j0 + j) * C_CH + c) << 10);
        const f32x4 a0 = r4[base + t];
        const f32x4 a1 = r4[base + NT + t];
        const f32x4 b0 = i4[base + t];
        const f32x4 b1 = i4[base + NT + t];
        ACC(a0, b0) ACC(a1, b1)
    }
#undef ACC

    // ---- block reduction (8 waves) -----------------------------------------
#pragma unroll
    for (int off = 32; off > 0; off >>= 1) {
        sr  += __shfl_down(sr,  off);
        si  += __shfl_down(si,  off);
        srr += __shfl_down(srr, off);
        sii += __shfl_down(sii, off);
        sri += __shfl_down(sri, off);
    }
    const int wave = t >> 6;
    if ((t & 63) == 0) {
        red[0][wave] = sr;  red[1][wave] = si;
        red[2][wave] = srr; red[3][wave] = sii; red[4][wave] = sri;
    }
    __syncthreads();

    // ---- cross-half combine + coefficients (thread 0) ----------------------
    if (t == 0) {
        float own[5];
#pragma unroll
        for (int k = 0; k < 5; ++k) {
            float acc = red[k][0];
#pragma unroll
            for (int w = 1; w < NT / 64; ++w) acc += red[k][w];
            own[k] = acc;
        }
#pragma unroll
        for (int k = 0; k < 5; ++k)
            __hip_atomic_store(&part[b * 5 + k], own[k],
                               __ATOMIC_RELAXED, __HIP_MEMORY_SCOPE_AGENT);
        __hip_atomic_store(&flag[b], 1,
                           __ATOMIC_RELEASE, __HIP_MEMORY_SCOPE_AGENT);

        const int ob = b ^ 1;
        while (__hip_atomic_load(&flag[ob],
                                 __ATOMIC_ACQUIRE, __HIP_MEMORY_SCOPE_AGENT) == 0) {
            __builtin_amdgcn_s_sleep(8);
        }
        float v[5];
#pragma unroll
        for (int k = 0; k < 5; ++k) {
            const float oth = __hip_atomic_load(&part[ob * 5 + k],
                                                __ATOMIC_RELAXED, __HIP_MEMORY_SCOPE_AGENT);
            v[k] = own[k] + oth;     // 2-term add: order-independent
        }

        const float invN = 1.0f / (float)N_PER_CH;
        const float mur = v[0] * invN;
        const float mui = v[1] * invN;
        const float Vrr = v[2] * invN - mur * mur + EPS_BN;
        const float Vii = v[3] * invN - mui * mui + EPS_BN;
        const float Vri = v[4] * invN - mur * mui;

        const float s      = sqrtf(Vrr * Vii - Vri * Vri);
        const float tt     = sqrtf(Vrr + Vii + 2.0f * s);
        const float inv_st = 1.0f / (s * tt);
        const float Rrr = (Vii + s) * inv_st;
        const float Rii = (Vrr + s) * inv_st;
        const float Rri = -Vri * inv_st;

        const float w00 = weight[0 * C_CH + c];
        const float w01 = weight[1 * C_CH + c];
        const float w10 = weight[2 * C_CH + c];
        const float w11 = weight[3 * C_CH + c];
        const float b0  = bias[c];
        const float b1  = bias[C_CH + c];

        const float Ar = w00 * Rrr + w01 * Rri;
        const float Br = w00 * Rri + w01 * Rii;
        const float Ai = w10 * Rrr + w11 * Rri;
        const float Bi = w10 * Rri + w11 * Rii;

        scoef[0] = Ar;
        scoef[1] = Br;
        scoef[2] = b0 - Ar * mur - Br * mui;
        scoef[3] = Ai;
        scoef[4] = Bi;
        scoef[5] = b1 - Ai * mur - Bi * mui;
    }
    __syncthreads();

    const float Ar = scoef[0], Br = scoef[1], Cr = scoef[2];
    const float Ai = scoef[3], Bi = scoef[4], Ci = scoef[5];

    f32x4* o4 = reinterpret_cast<f32x4*>(out);
    const size_t n4 = N_TOT / 4;

#define APPLY_STORE(a, bb, idx)                                    \
    {   f32x4 u, w_;                                               \
        u.x = Ar*a.x + Br*bb.x + Cr;  u.y = Ar*a.y + Br*bb.y + Cr; \
        u.z = Ar*a.z + Br*bb.z + Cr;  u.w = Ar*a.w + Br*bb.w + Cr; \
        w_.x = Ai*a.x + Bi*bb.x + Ci; w_.y = Ai*a.y + Bi*bb.y + Ci;\
        w_.z = Ai*a.z + Bi*bb.z + Ci; w_.w = Ai*a.w + Bi*bb.w + Ci;\
        __builtin_nontemporal_store(u,  &o4[idx]);                 \
        __builtin_nontemporal_store(w_, &o4[n4 + idx]); }

#define UNPK(p0, p1, dst) { dst.x = blo(p0); dst.y = bhi(p0); dst.z = blo(p1); dst.w = bhi(p1); }

    // ---- phase 2a: streamed slabs FIRST (L3-hot re-read) -------------------
#pragma unroll
    for (int j = RS + LS; j < HALF; ++j) {
        const size_t base = ((size_t)((j0 + j) * C_CH + c) << 10);
        const f32x4 a0 = r4[base + t];
        const f32x4 a1 = r4[base + NT + t];
        const f32x4 b0 = i4[base + t];
        const f32x4 b1 = i4[base + NT + t];
        APPLY_STORE(a0, b0, base + t)
        APPLY_STORE(a1, b1, base + NT + t)
    }
    // ---- phase 2b: LDS-resident slabs --------------------------------------
#pragma unroll
    for (int j = 0; j < LS; ++j) {
        const size_t base = ((size_t)((j0 + RS + j) * C_CH + c) << 10);
        f32x4 a0, a1, b0, b1;
        UNPK(lpk[j][0][t], lpk[j][1][t], a0)
        UNPK(lpk[j][2][t], lpk[j][3][t], a1)
        UNPK(lpk[j][4][t], lpk[j][5][t], b0)
        UNPK(lpk[j][6][t], lpk[j][7][t], b1)
        APPLY_STORE(a0, b0, base + t)
        APPLY_STORE(a1, b1, base + NT + t)
    }
    // ---- phase 2c: register-resident slabs ---------------------------------
#pragma unroll
    for (int j = 0; j < RS; ++j) {
        const size_t base = ((size_t)((j0 + j) * C_CH + c) << 10);
        f32x4 a0, a1, b0, b1;
        UNPK(rp[j][0], rp[j][1], a0)
        UNPK(rp[j][2], rp[j][3], a1)
        UNPK(rp[j][4], rp[j][5], b0)
        UNPK(rp[j][6], rp[j][7], b1)
        APPLY_STORE(a0, b0, base + t)
        APPLY_STORE(a1, b1, base + NT + t)
    }
#undef APPLY_STORE
#undef UNPK
}

extern "C" void kernel_launch(void* const* d_in, const int* in_sizes, int n_in,
                              void* d_out, int out_size, void* d_ws, size_t ws_size,
                              hipStream_t stream) {
    const float* xr     = (const float*)d_in[0];
    const float* xi     = (const float*)d_in[1];
    const float* weight = (const float*)d_in[2];
    const float* bias   = (const float*)d_in[3];
    float* out = (float*)d_out;

    int*   flag = (int*)d_ws;                   // [512]
    float* part = (float*)((char*)d_ws + 2048); // [512][5]

    // flags must be zero at every call (ws is not re-poisoned between replays)
    hipMemsetAsync(d_ws, 0, 2048, stream);

    cbn_dual<<<512, NT, 0, stream>>>(xr, xi, weight, bias, out, part, flag);
}

// Round 15
// 119.528 us; speedup vs baseline: 1.2081x; 1.2081x over previous
//
#include <hip/hip_runtime.h>
#include <math.h>

#define C_CH   256
#define HW     4096              // H*W
#define B_N    32
#define N_PER_CH (B_N * HW)      // 131072
#define N_TOT  ((size_t)B_N * C_CH * HW) // 33554432 per plane
#define EPS_BN 1e-5f

#define NT 512                   // threads per block
#define HALF 16                  // slabs per block (half a channel)
#define RS 9                     // slabs retained in registers (bf16, 72 u32)
#define LS 4                     // slabs retained in LDS (bf16, 64 KiB)
// streamed = 16-9-4 = 3 slabs/block (48 MB chip-wide -> L3-served re-read)

typedef float f32x4 __attribute__((ext_vector_type(4)));

// bf16 round-to-nearest-even pack/unpack (2 values per u32)
__device__ __forceinline__ unsigned pk(float a, float b) {
    unsigned ua = __float_as_uint(a);
    unsigned ub = __float_as_uint(b);
    ua += 0x7fffu + ((ua >> 16) & 1u);
    ub += 0x7fffu + ((ub >> 16) & 1u);
    return (ua >> 16) | (ub & 0xffff0000u);
}
__device__ __forceinline__ float blo(unsigned p) { return __uint_as_float(p << 16); }
__device__ __forceinline__ float bhi(unsigned p) { return __uint_as_float(p & 0xffff0000u); }

// ---------------------------------------------------------------------------
// 16-waves/CU spill-free retention: 2 x 512-thread blocks per CU.
// VGPR-cap forensics (R6/R8/R10/R13/R14): the toolchain behaves as if the
// 2nd __launch_bounds__ arg were CUDA-style MIN BLOCKS per CU:
//   (512,4) -> 32 waves/CU -> cap 64 (R14 spilled);
//   (512,2) -> 16 waves/CU -> cap 128 (R11/R12 ran, but demanded >128);
//   no arg  -> compiler free choice (R8: 144, no spill, but then only 1
//              block/CU fits by VGPR -> 8 waves).
// This round: (512,2) with demand ~107 < 128 -> spill-free AND 16 waves/CU.
// Block b = (channel c=b>>1, half h=b&1) owns slabs h*16..h*16+15; thread
// owns f32x4 t and 512+t of each plane.
//   regs: 9 slabs (rp[9][8] = 72 data u32 + ~35 ovh ~= 107 <= 128)
//   LDS : 4 slabs ([4][8][512] u32 = 64 KiB; 2 blocks = 128 <= 160)
//   HBM : 3 slabs streamed temporal, re-read FIRST in phase 2 (48 MB, L3)
// Cross-half combine: R8's flag-spin (device-scope, 2-term add, all 512
// blocks co-resident).  Stats from full-precision values; retained copy
// bf16 (absmax 0.031, threshold 0.085).  nt stores throughout.
// Output layout [2,B,C,H,W]: real plane, imag plane at +N_TOT.
// ---------------------------------------------------------------------------
__global__ __launch_bounds__(NT, 2) void cbn_dual2(
    const float* __restrict__ xr, const float* __restrict__ xi,
    const float* __restrict__ weight,   // [2,2,C]
    const float* __restrict__ bias,     // [2,C]
    float* __restrict__ out,
    float* __restrict__ part,           // [512][5]
    int*   __restrict__ flag)           // [512]
{
    const int b  = blockIdx.x;
    const int c  = b >> 1;
    const int h  = b & 1;
    const int t  = threadIdx.x;
    const int j0 = h * HALF;

    const f32x4* r4 = reinterpret_cast<const f32x4*>(xr);
    const f32x4* i4 = reinterpret_cast<const f32x4*>(xi);

    __shared__ unsigned lpk[LS][8][NT];
    __shared__ float red[5][NT / 64];
    __shared__ float scoef[6];

    float sr = 0.f, si = 0.f, srr = 0.f, sii = 0.f, sri = 0.f;
    unsigned rp[RS][8];

#define ACC(a, bb)                                              \
    sr  += a.x + a.y + a.z + a.w;                               \
    si  += bb.x + bb.y + bb.z + bb.w;                           \
    srr += a.x*a.x + a.y*a.y + a.z*a.z + a.w*a.w;               \
    sii += bb.x*bb.x + bb.y*bb.y + bb.z*bb.z + bb.w*bb.w;       \
    sri += a.x*bb.x + a.y*bb.y + a.z*bb.z + a.w*bb.w;

    // ---- phase 1a: register-retained slabs (bf16-packed, nt loads) ---------
#pragma unroll
    for (int j = 0; j < RS; ++j) {
        const size_t base = ((size_t)((j0 + j) * C_CH + c) << 10);
        const f32x4 a0 = __builtin_nontemporal_load(&r4[base + t]);
        const f32x4 a1 = __builtin_nontemporal_load(&r4[base + NT + t]);
        const f32x4 b0 = __builtin_nontemporal_load(&i4[base + t]);
        const f32x4 b1 = __builtin_nontemporal_load(&i4[base + NT + t]);
        rp[j][0] = pk(a0.x, a0.y); rp[j][1] = pk(a0.z, a0.w);
        rp[j][2] = pk(a1.x, a1.y); rp[j][3] = pk(a1.z, a1.w);
        rp[j][4] = pk(b0.x, b0.y); rp[j][5] = pk(b0.z, b0.w);
        rp[j][6] = pk(b1.x, b1.y); rp[j][7] = pk(b1.z, b1.w);
        ACC(a0, b0) ACC(a1, b1)
    }
    // ---- phase 1b: LDS-retained slabs (bf16-packed, nt loads) --------------
#pragma unroll
    for (int j = 0; j < LS; ++j) {
        const size_t base = ((size_t)((j0 + RS + j) * C_CH + c) << 10);
        const f32x4 a0 = __builtin_nontemporal_load(&r4[base + t]);
        const f32x4 a1 = __builtin_nontemporal_load(&r4[base + NT + t]);
        const f32x4 b0 = __builtin_nontemporal_load(&i4[base + t]);
        const f32x4 b1 = __builtin_nontemporal_load(&i4[base + NT + t]);
        lpk[j][0][t] = pk(a0.x, a0.y); lpk[j][1][t] = pk(a0.z, a0.w);
        lpk[j][2][t] = pk(a1.x, a1.y); lpk[j][3][t] = pk(a1.z, a1.w);
        lpk[j][4][t] = pk(b0.x, b0.y); lpk[j][5][t] = pk(b0.z, b0.w);
        lpk[j][6][t] = pk(b1.x, b1.y); lpk[j][7][t] = pk(b1.z, b1.w);
        ACC(a0, b0) ACC(a1, b1)
    }
    // ---- phase 1c: streamed slabs (temporal -> allocate L3 for re-read) ----
#pragma unroll
    for (int j = RS + LS; j < HALF; ++j) {
        const size_t base = ((size_t)((j0 + j) * C_CH + c) << 10);
        const f32x4 a0 = r4[base + t];
        const f32x4 a1 = r4[base + NT + t];
        const f32x4 b0 = i4[base + t];
        const f32x4 b1 = i4[base + NT + t];
        ACC(a0, b0) ACC(a1, b1)
    }
#undef ACC

    // ---- block reduction (8 waves) -----------------------------------------
#pragma unroll
    for (int off = 32; off > 0; off >>= 1) {
        sr  += __shfl_down(sr,  off);
        si  += __shfl_down(si,  off);
        srr += __shfl_down(srr, off);
        sii += __shfl_down(sii, off);
        sri += __shfl_down(sri, off);
    }
    const int wave = t >> 6;
    if ((t & 63) == 0) {
        red[0][wave] = sr;  red[1][wave] = si;
        red[2][wave] = srr; red[3][wave] = sii; red[4][wave] = sri;
    }
    __syncthreads();

    // ---- cross-half combine + coefficients (thread 0) ----------------------
    if (t == 0) {
        float own[5];
#pragma unroll
        for (int k = 0; k < 5; ++k) {
            float acc = red[k][0];
#pragma unroll
            for (int w = 1; w < NT / 64; ++w) acc += red[k][w];
            own[k] = acc;
        }
#pragma unroll
        for (int k = 0; k < 5; ++k)
            __hip_atomic_store(&part[b * 5 + k], own[k],
                               __ATOMIC_RELAXED, __HIP_MEMORY_SCOPE_AGENT);
        __hip_atomic_store(&flag[b], 1,
                           __ATOMIC_RELEASE, __HIP_MEMORY_SCOPE_AGENT);

        const int ob = b ^ 1;
        while (__hip_atomic_load(&flag[ob],
                                 __ATOMIC_ACQUIRE, __HIP_MEMORY_SCOPE_AGENT) == 0) {
            __builtin_amdgcn_s_sleep(8);
        }
        float v[5];
#pragma unroll
        for (int k = 0; k < 5; ++k) {
            const float oth = __hip_atomic_load(&part[ob * 5 + k],
                                                __ATOMIC_RELAXED, __HIP_MEMORY_SCOPE_AGENT);
            v[k] = own[k] + oth;     // 2-term add: order-independent
        }

        const float invN = 1.0f / (float)N_PER_CH;
        const float mur = v[0] * invN;
        const float mui = v[1] * invN;
        const float Vrr = v[2] * invN - mur * mur + EPS_BN;
        const float Vii = v[3] * invN - mui * mui + EPS_BN;
        const float Vri = v[4] * invN - mur * mui;

        const float s      = sqrtf(Vrr * Vii - Vri * Vri);
        const float tt     = sqrtf(Vrr + Vii + 2.0f * s);
        const float inv_st = 1.0f / (s * tt);
        const float Rrr = (Vii + s) * inv_st;
        const float Rii = (Vrr + s) * inv_st;
        const float Rri = -Vri * inv_st;

        const float w00 = weight[0 * C_CH + c];
        const float w01 = weight[1 * C_CH + c];
        const float w10 = weight[2 * C_CH + c];
        const float w11 = weight[3 * C_CH + c];
        const float b0  = bias[c];
        const float b1  = bias[C_CH + c];

        const float Ar = w00 * Rrr + w01 * Rri;
        const float Br = w00 * Rri + w01 * Rii;
        const float Ai = w10 * Rrr + w11 * Rri;
        const float Bi = w10 * Rri + w11 * Rii;

        scoef[0] = Ar;
        scoef[1] = Br;
        scoef[2] = b0 - Ar * mur - Br * mui;
        scoef[3] = Ai;
        scoef[4] = Bi;
        scoef[5] = b1 - Ai * mur - Bi * mui;
    }
    __syncthreads();

    const float Ar = scoef[0], Br = scoef[1], Cr = scoef[2];
    const float Ai = scoef[3], Bi = scoef[4], Ci = scoef[5];

    f32x4* o4 = reinterpret_cast<f32x4*>(out);
    const size_t n4 = N_TOT / 4;

#define APPLY_STORE(a, bb, idx)                                    \
    {   f32x4 u, w_;                                               \
        u.x = Ar*a.x + Br*bb.x + Cr;  u.y = Ar*a.y + Br*bb.y + Cr; \
        u.z = Ar*a.z + Br*bb.z + Cr;  u.w = Ar*a.w + Br*bb.w + Cr; \
        w_.x = Ai*a.x + Bi*bb.x + Ci; w_.y = Ai*a.y + Bi*bb.y + Ci;\
        w_.z = Ai*a.z + Bi*bb.z + Ci; w_.w = Ai*a.w + Bi*bb.w + Ci;\
        __builtin_nontemporal_store(u,  &o4[idx]);                 \
        __builtin_nontemporal_store(w_, &o4[n4 + idx]); }

#define UNPK(p0, p1, dst) { dst.x = blo(p0); dst.y = bhi(p0); dst.z = blo(p1); dst.w = bhi(p1); }

    // ---- phase 2a: streamed slabs FIRST (L3-hot re-read) -------------------
#pragma unroll
    for (int j = RS + LS; j < HALF; ++j) {
        const size_t base = ((size_t)((j0 + j) * C_CH + c) << 10);
        const f32x4 a0 = r4[base + t];
        const f32x4 a1 = r4[base + NT + t];
        const f32x4 b0 = i4[base + t];
        const f32x4 b1 = i4[base + NT + t];
        APPLY_STORE(a0, b0, base + t)
        APPLY_STORE(a1, b1, base + NT + t)
    }
    // ---- phase 2b: LDS-resident slabs --------------------------------------
#pragma unroll
    for (int j = 0; j < LS; ++j) {
        const size_t base = ((size_t)((j0 + RS + j) * C_CH + c) << 10);
        f32x4 a0, a1, b0, b1;
        UNPK(lpk[j][0][t], lpk[j][1][t], a0)
        UNPK(lpk[j][2][t], lpk[j][3][t], a1)
        UNPK(lpk[j][4][t], lpk[j][5][t], b0)
        UNPK(lpk[j][6][t], lpk[j][7][t], b1)
        APPLY_STORE(a0, b0, base + t)
        APPLY_STORE(a1, b1, base + NT + t)
    }
    // ---- phase 2c: register-resident slabs ---------------------------------
#pragma unroll
    for (int j = 0; j < RS; ++j) {
        const size_t base = ((size_t)((j0 + j) * C_CH + c) << 10);
        f32x4 a0, a1, b0, b1;
        UNPK(rp[j][0], rp[j][1], a0)
        UNPK(rp[j][2], rp[j][3], a1)
        UNPK(rp[j][4], rp[j][5], b0)
        UNPK(rp[j][6], rp[j][7], b1)
        APPLY_STORE(a0, b0, base + t)
        APPLY_STORE(a1, b1, base + NT + t)
    }
#undef APPLY_STORE
#undef UNPK
}

extern "C" void kernel_launch(void* const* d_in, const int* in_sizes, int n_in,
                              void* d_out, int out_size, void* d_ws, size_t ws_size,
                              hipStream_t stream) {
    const float* xr     = (const float*)d_in[0];
    const float* xi     = (const float*)d_in[1];
    const float* weight = (const float*)d_in[2];
    const float* bias   = (const float*)d_in[3];
    float* out = (float*)d_out;

    int*   flag = (int*)d_ws;                   // [512]
    float* part = (float*)((char*)d_ws + 2048); // [512][5]

    // flags must be zero at every call (ws is not re-poisoned between replays)
    hipMemsetAsync(d_ws, 0, 2048, stream);

    cbn_dual2<<<512, NT, 0, stream>>>(xr, xi, weight, bias, out, part, flag);
}